// Round 6
// baseline (4727.739 us; speedup 1.0000x reference)
//
#include <hip/hip_runtime.h>

// TimeLSTM on MI355X (gfx950). B=64,S=1024,D=128,H=256.
// ROUND-11: round-10 (1024-thr redesign) reached 4.32ms but VGPR_Count=64
// (= the 16 pinned chunks ALONE) + 10.1k cyc/step (= the pins-dead traffic
// model) prove the EMPTY asm volatile pin was elided before regalloc — an
// empty asm has no machine instruction to anchor, so the in-loop uses were
// rematerialized as fresh WX loads (L2-resident => invisible in FETCH_SIZE).
// FIX: pin via asm volatile("s_nop 0" : "+v"(w)) — a real emitted
// instruction with a tied def+use cannot be elided/duplicated/remat'd, so
// the weight values MUST stay in VGPRs across the scan loop.
// Rebalanced partition per thread (40 chunks): 20 pinned VGPR (80 regs) +
// 9 LDS slots (144KB) + 11 streamed from L2 (176KB/step/CU, 4-deep pipe).
// Working set ~121 regs <= the 128/wave budget the backend grants.
// 64 blocks x 1024 threads (16 waves = 4/SIMD x 128 regs = full file).

#define B_ 64
#define S_ 1024
#define D_ 128
#define H_ 256
#define FH_ 1024
// h(512) c(512) pg(4KB) pd(4KB) wl(9*16KB)
#define SMEM_BYTES (1024 + 4096 + 4096 + 9 * 1024 * 16)   // 156672 <= 160 KiB

typedef _Float16 half2_t __attribute__((ext_vector_type(2)));
typedef _Float16 half8_t __attribute__((ext_vector_type(8)));
typedef float    f32x4   __attribute__((ext_vector_type(4)));

union HW { half8_t v; half2_t p[4]; };
union U32H2 { unsigned int u; half2_t h; };

__device__ inline float dot2acc(half2_t a, half2_t b, float c) {
#if __has_builtin(__builtin_amdgcn_fdot2)
    return __builtin_amdgcn_fdot2(a, b, c, false);
#else
    return c + (float)a[0] * (float)b[0] + (float)a[1] * (float)b[1];
#endif
}

__device__ inline float sigmoid_f(float x) { return 1.f / (1.f + __expf(-x)); }
__device__ inline float tanh_f(float x)    { return 1.f - 2.f / (__expf(2.f * x) + 1.f); }

// ---------------------------------------------------------------------------
// Pack. WX slot-major: WX[slot][1024][8], slot in [0,40):
//   slot<32 : gate chunk — WX[c][t] = W_all[row t][c*8 .. c*8+8)
//   32..39  : W_d slice  — WX[32+k][(g<<8)|e] = W_d[e][g*64 + k*8 .. +8)
// ---------------------------------------------------------------------------
__global__ __launch_bounds__(256) void pack_kernel(
    const float* __restrict__ Wall, const float* __restrict__ Wd,
    const float* __restrict__ Uall, const float* __restrict__ ts,
    _Float16* __restrict__ WX, _Float16* __restrict__ U16,
    float* __restrict__ decay)
{
    int idx = blockIdx.x * 256 + threadIdx.x;
    if (idx < 40960) {
        int slot = idx >> 10, t = idx & 1023;
        const float* src;
        if (slot < 32) {
            src = Wall + (size_t)t * H_ + slot * 8;
        } else {
            int e = t & 255, g = t >> 8, k = slot - 32;
            src = Wd + (size_t)e * H_ + g * 64 + k * 8;
        }
        _Float16* dst = WX + ((size_t)slot * 1024 + t) * 8;
        #pragma unroll
        for (int j = 0; j < 8; j++) dst[j] = (_Float16)src[j];
    } else if (idx < 40960 + 131072) {
        int i = idx - 40960;
        U16[i] = (_Float16)Uall[i];
    } else if (idx < 40960 + 131072 + 65536) {
        int i = idx - 172032;
        int bb = i >> 10, s = i & 1023;
        float d = 1.f;
        if (s > 0) {
            float dt = ts[bb * S_ + s] - ts[bb * S_ + s - 1];
            dt = fmaxf(dt, 1e-6f);
            d = 1.f / logf(2.718281828459045f + dt);
        }
        decay[i] = d;
    }
}

// ---------------------------------------------------------------------------
// u GEMM via MFMA 16x16x32 f16. Stores u PLAIN: u16[row][col], col = gate-row
// index in [0,1024) — the scan's thread t reads u16[s][t] fully coalesced.
// ---------------------------------------------------------------------------
__global__ __launch_bounds__(256) void u_gemm_mfma(
    const float* __restrict__ x, const _Float16* __restrict__ U16,
    const float* __restrict__ Ub, _Float16* __restrict__ u16)
{
    int wave = threadIdx.x >> 6, lane = threadIdx.x & 63;
    size_t row0 = (size_t)blockIdx.x * 64 + wave * 16;
    int n0 = blockIdx.y * 256;
    int am = lane & 15;
    int ak = (lane >> 4) * 8;
    const float* xr = x + (row0 + am) * D_ + ak;

    f32x4 acc[16];
    #pragma unroll
    for (int nt = 0; nt < 16; nt++) acc[nt] = (f32x4){0.f, 0.f, 0.f, 0.f};

    #pragma unroll
    for (int kc = 0; kc < 4; kc++) {
        half8_t a;
        #pragma unroll
        for (int e = 0; e < 8; e++) a[e] = (_Float16)xr[kc * 32 + e];
        #pragma unroll
        for (int nt = 0; nt < 16; nt++) {
            half8_t bfr = *(const half8_t*)(U16 + (size_t)(n0 + nt * 16 + am) * D_ + kc * 32 + ak);
            acc[nt] = __builtin_amdgcn_mfma_f32_16x16x32_f16(a, bfr, acc[nt], 0, 0, 0);
        }
    }

    int cr = (lane >> 4) * 4;
    #pragma unroll
    for (int nt = 0; nt < 16; nt++) {
        int col = n0 + nt * 16 + am;
        float bias = Ub[col];
        #pragma unroll
        for (int i = 0; i < 4; i++) {
            u16[(row0 + cr + i) * (size_t)FH_ + col] = (_Float16)(acc[nt][i] + bias);
        }
    }
}

// ---------------------------------------------------------------------------
// Scan. 64 blocks x 1024 threads (16 waves, 4/SIMD, full 512-reg file).
// ---------------------------------------------------------------------------
__global__ void __launch_bounds__(1024)
scan_kernel(
    const _Float16* __restrict__ u16, const _Float16* __restrict__ WX,
    const float* __restrict__ Wb, const float* __restrict__ Wdb,
    const float* __restrict__ decay, float* __restrict__ out)
{
    int b = blockIdx.x, t = threadIdx.x;
    int e = t & 255, g = t >> 8, lane = t & 63;

    extern __shared__ __align__(16) char smem[];
    _Float16* h16 = (_Float16*)smem;              // [256] fp16
    _Float16* c16 = (_Float16*)(smem + 512);      // [256] fp16
    float*    pg  = (float*)(smem + 1024);        // [1024] gate pre-acts
    float*    pd  = (float*)(smem + 5120);        // [1024] W_d partials
    half8_t*  wl  = (half8_t*)(smem + 9216);      // 9 slots x 1024 thr

    const half8_t* __restrict__ WX8 = (const half8_t*)WX;

    // ---- LDS weights: slots 20..28 (gate chunks 20..28) ----
    #pragma unroll
    for (int j = 0; j < 9; j++) wl[(size_t)j * 1024 + t] = WX8[(size_t)(20 + j) * 1024 + t];

    // ---- pinned weights: slots 0..19 (gate chunks 0..19), 80 VGPRs.
    //      Pin body is a REAL instruction (s_nop) with tied def+use: cannot
    //      be elided (unlike the empty-string asm, which LLVM dropped) nor
    //      rematerialized — the 80 regs stay live across the scan loop. ----
    half8_t wA[20];
    #pragma unroll
    for (int c = 0; c < 20; c++) wA[c] = WX8[(size_t)c * 1024 + t];
    #pragma unroll
    for (int c = 0; c < 20; c++) asm volatile("s_nop 0" : "+v"(wA[c]));

    float bA   = Wb[t];
    float wdbt = (t < 256) ? Wdb[e] : 0.f;

    if (t < 256) { h16[t] = (_Float16)0.f; c16[t] = (_Float16)0.f; }
    float c_reg = 0.f, hn = 0.f;
    __syncthreads();

    const _Float16* __restrict__ ub   = u16 + (size_t)b * S_ * FH_;
    const float*    __restrict__ db   = decay + (size_t)b * S_;
    float*          __restrict__ outb = out + (size_t)b * S_ * H_;
    // streamed slots 29..39: gate chunks 29..31 (3) + W_d slices 0..7 (8)
    const half8_t*  __restrict__ sp   = WX8 + (size_t)29 * 1024 + t;

    for (int s = 0; s < S_; s++) {
        float uval = (float)ub[(size_t)s * FH_ + t];

        // per-lane h/c slices (the ONLY LDS state reads; broadcast is readlane)
        uint2 hp = *(const uint2*)((const char*)h16 + 8 * lane);            // h[4l..4l+4)
        unsigned int cp = *(const unsigned int*)((const char*)c16 + 4 * ((g << 5) + (lane & 31)));

        // rolling 4-deep stream pipeline over 11 chunks
        half8_t sw[4];
        #pragma unroll
        for (int j = 0; j < 4; j++) sw[j] = sp[(size_t)j * 1024];

        float aA = 0.f, aD = 0.f;

        // gate-row dot: 32 chunks; h chunk c broadcast from lanes 2c, 2c+1
        #pragma unroll
        for (int c = 0; c < 32; c++) {
            U32H2 d0, d1, d2, d3;
            d0.u = __builtin_amdgcn_readlane(hp.x, 2 * c);
            d1.u = __builtin_amdgcn_readlane(hp.y, 2 * c);
            d2.u = __builtin_amdgcn_readlane(hp.x, 2 * c + 1);
            d3.u = __builtin_amdgcn_readlane(hp.y, 2 * c + 1);
            half8_t w;
            if (c < 20) {
                w = wA[c];
            } else if (c < 29) {
                w = wl[(size_t)(c - 20) * 1024 + t];
            } else {
                int i = c - 29;
                w = sw[i & 3];
                if (i + 4 < 11) sw[i & 3] = sp[(size_t)(i + 4) * 1024];
            }
            HW uw; uw.v = w;
            aA = dot2acc(d0.h, uw.p[0], aA);
            aA = dot2acc(d1.h, uw.p[1], aA);
            aA = dot2acc(d2.h, uw.p[2], aA);
            aA = dot2acc(d3.h, uw.p[3], aA);
        }
        // W_d slice g: 8 chunks; c chunk k broadcast from lanes 4k..4k+3
        #pragma unroll
        for (int k = 0; k < 8; k++) {
            U32H2 d0, d1, d2, d3;
            d0.u = __builtin_amdgcn_readlane(cp, 4 * k);
            d1.u = __builtin_amdgcn_readlane(cp, 4 * k + 1);
            d2.u = __builtin_amdgcn_readlane(cp, 4 * k + 2);
            d3.u = __builtin_amdgcn_readlane(cp, 4 * k + 3);
            int i = 3 + k;
            half8_t w = sw[i & 3];
            if (i + 4 < 11) sw[i & 3] = sp[(size_t)(i + 4) * 1024];
            HW uw; uw.v = w;
            aD = dot2acc(d0.h, uw.p[0], aD);
            aD = dot2acc(d1.h, uw.p[1], aD);
            aD = dot2acc(d2.h, uw.p[2], aD);
            aD = dot2acc(d3.h, uw.p[3], aD);
        }

        pg[t] = aA + bA + uval;
        pd[t] = aD;
        __syncthreads();

        if (t < 256) {
            float f_ = pg[e], i_ = pg[256 + e], o_ = pg[512 + e], ct = pg[768 + e];
            float ad = pd[e] + pd[256 + e] + pd[512 + e] + pd[768 + e] + wdbt;
            float dly  = db[s];
            float cs   = tanh_f(ad);
            float cadj = (c_reg - cs) + cs * dly;
            float cn   = sigmoid_f(f_) * cadj + sigmoid_f(i_) * tanh_f(ct);
            hn = sigmoid_f(o_) * tanh_f(cn);
            c_reg = cn;
            outb[(size_t)s * H_ + e] = hn;
            h16[e] = (_Float16)hn;
            c16[e] = (_Float16)cn;
        }
        __syncthreads();
    }

    if (t < 256) {
        out[(size_t)B_ * S_ * H_ + (size_t)b * H_ + e] = hn;
        out[(size_t)B_ * S_ * H_ + (size_t)B_ * H_ + (size_t)b * H_ + e] = c_reg;
    }
}

// ---------------------------------------------------------------------------
extern "C" void kernel_launch(void* const* d_in, const int* in_sizes, int n_in,
                              void* d_out, int out_size, void* d_ws, size_t ws_size,
                              hipStream_t stream) {
    const float* inputs     = (const float*)d_in[0];   // [B,S,D]
    const float* timestamps = (const float*)d_in[1];   // [B,S]
    const float* W_all_w    = (const float*)d_in[2];   // [4H,H]
    const float* W_all_b    = (const float*)d_in[3];   // [4H]
    const float* U_all_w    = (const float*)d_in[4];   // [4H,D]
    const float* U_all_b    = (const float*)d_in[5];   // [4H]
    const float* W_d_w      = (const float*)d_in[6];   // [H,H]
    const float* W_d_b      = (const float*)d_in[7];   // [H]
    float* out = (float*)d_out;

    char* p = (char*)d_ws;
    _Float16* u16 = (_Float16*)p;   p += (size_t)B_ * S_ * FH_ * 2;   // 128 MiB
    _Float16* WX  = (_Float16*)p;   p += (size_t)40 * 1024 * 8 * 2;   // 640 KiB
    _Float16* U16 = (_Float16*)p;   p += (size_t)FH_ * D_ * 2;        // 256 KiB
    float*    dec = (float*)p;                                         // 256 KiB

    (void)hipFuncSetAttribute((const void*)scan_kernel,
                              hipFuncAttributeMaxDynamicSharedMemorySize,
                              SMEM_BYTES);

    pack_kernel<<<dim3(928), dim3(256), 0, stream>>>(
        W_all_w, W_d_w, U_all_w, timestamps, WX, U16, dec);
    u_gemm_mfma<<<dim3(1024, 4), dim3(256), 0, stream>>>(
        inputs, U16, U_all_b, u16);
    scan_kernel<<<dim3(B_), dim3(1024), SMEM_BYTES, stream>>>(
        u16, WX, W_all_b, W_d_b, dec, out);
}